// Round 2
// baseline (1859.382 us; speedup 1.0000x reference)
//
#include <hip/hip_runtime.h>
#include <hip/hip_bf16.h>
#include <cstdint>
#include <cstddef>

// Problem dims (fixed by setup_inputs)
#define TDIM 2048
#define HDIM 4096
#define MDIM 14336

typedef __attribute__((ext_vector_type(8))) __bf16 bf16x8;
typedef __attribute__((ext_vector_type(4))) float f32x4;

__device__ __constant__ float NF4_LUT[16] = {
    -1.0f, -0.6961928009986877f, -0.5250730514526367f, -0.39491748809814453f,
    -0.28444138169288635f, -0.18477343022823334f, -0.09105003625154495f, 0.0f,
    0.07958029955625534f, 0.16093020141124725f, 0.24611230194568634f,
    0.33791524171829224f, 0.44070982933044434f, 0.5626170039176941f,
    0.7229568362236023f, 1.0f};

__device__ __forceinline__ void g2l16(const void* g, void* l) {
  __builtin_amdgcn_global_load_lds(
      (const __attribute__((address_space(1))) unsigned int*)g,
      (__attribute__((address_space(3))) unsigned int*)l, 16, 0, 0);
}

// ------------------------------------------------------------ x f32 -> bf16
__global__ __launch_bounds__(256) void f32_to_bf16_k(
    const float* __restrict__ in, __hip_bfloat16* __restrict__ out, int n8) {
  for (int i = blockIdx.x * 256 + threadIdx.x; i < n8; i += gridDim.x * 256) {
    const float4* p = (const float4*)(in + (size_t)i * 8);
    float4 a = p[0], b = p[1];
    union { __hip_bfloat16 h[8]; int4 v; } u;
    u.h[0] = __float2bfloat16(a.x);
    u.h[1] = __float2bfloat16(a.y);
    u.h[2] = __float2bfloat16(a.z);
    u.h[3] = __float2bfloat16(a.w);
    u.h[4] = __float2bfloat16(b.x);
    u.h[5] = __float2bfloat16(b.y);
    u.h[6] = __float2bfloat16(b.z);
    u.h[7] = __float2bfloat16(b.w);
    *(int4*)(out + (size_t)i * 8) = u.v;
  }
}

// --------------------------------------------------- NF4 dequant -> bf16 W
__global__ __launch_bounds__(256) void dequant_nf4_k(
    const int* __restrict__ codes, const float* __restrict__ absmax,
    __hip_bfloat16* __restrict__ W, int K) {
  __shared__ float lut[16];
  if (threadIdx.x < 16) lut[threadIdx.x] = NF4_LUT[threadIdx.x];
  __syncthreads();
  const int row = blockIdx.x;
  const int K8 = K >> 3;
  const size_t rbase = (size_t)row * K;
  for (int c8 = threadIdx.x; c8 < K8; c8 += 256) {
    const int col = c8 << 3;
    const float am = absmax[(size_t)row * (K >> 6) + (col >> 6)];
    const int4* cp = (const int4*)(codes + rbase + col);
    int4 ca = cp[0], cb = cp[1];
    union { __hip_bfloat16 h[8]; int4 v; } u;
    u.h[0] = __float2bfloat16(lut[ca.x & 15] * am);
    u.h[1] = __float2bfloat16(lut[ca.y & 15] * am);
    u.h[2] = __float2bfloat16(lut[ca.z & 15] * am);
    u.h[3] = __float2bfloat16(lut[ca.w & 15] * am);
    u.h[4] = __float2bfloat16(lut[cb.x & 15] * am);
    u.h[5] = __float2bfloat16(lut[cb.y & 15] * am);
    u.h[6] = __float2bfloat16(lut[cb.z & 15] * am);
    u.h[7] = __float2bfloat16(lut[cb.w & 15] * am);
    *(int4*)(W + rbase + col) = u.v;
  }
}

// ------------------------------------------------------- 8-phase 256² GEMM
// C[M,N] (+)= A[M,K] @ B[N,K]^T, bf16 in, f32 acc. 512 thr = 8 waves (2x4).
// LDS 128KB: [A | B], each 2 buf x 2 half x (128 rows x 128B swizzled).
// Wave (wm,wn): C rows (mh*128 + wm*64 + ...), cols (nh*128 + wn*32 + ...).
// Quadrant (mh,nh) reads A-half mh, B-half nh only -> half-granular staging.
// Stage map (iteration = tiles t[buf0], t+1[buf1]):
//  p0:A(t+1,h1,b1) p1:B(t+1,h1,b1) p2:A(t+2,h0,b0) p3:B(t+2,h0,b0)+vmcnt(4)
//  p4:A(t+2,h1,b0) p5:B(t+2,h1,b0) p6:A(t+3,h0,b1) p7:B(t+3,h0,b1)+vmcnt(4)
// Each wait retires the tile read starting NEXT phase; 4 younger loads stay
// in flight (never vmcnt(0) in steady state).
template <int B_, int MH, int NH, int VM, typename F>
__device__ __forceinline__ void phase8(const char* aRd, const char* bRd,
                                       f32x4 (&acc)[8][4], F&& stage) {
  bf16x8 af[4][2], bv[2][2];
  const char* ab = aRd + B_ * 32768 + MH * 16384;
  const char* bb = bRd + B_ * 32768 + NH * 16384;
#pragma unroll
  for (int q = 0; q < 4; ++q) {
    af[q][0] = *(const bf16x8*)((uintptr_t)(ab + q * 2048));
    af[q][1] = *(const bf16x8*)((uintptr_t)(ab + q * 2048) ^ 64);
  }
#pragma unroll
  for (int j = 0; j < 2; ++j) {
    bv[j][0] = *(const bf16x8*)((uintptr_t)(bb + j * 2048));
    bv[j][1] = *(const bf16x8*)((uintptr_t)(bb + j * 2048) ^ 64);
  }
  stage();
  if (VM == 4) asm volatile("s_waitcnt vmcnt(4)" ::: "memory");
  if (VM == 0) asm volatile("s_waitcnt vmcnt(0)" ::: "memory");
  asm volatile("" ::: "memory");
  __builtin_amdgcn_s_barrier();
  asm volatile("" ::: "memory");
  __builtin_amdgcn_s_setprio(1);
#pragma unroll
  for (int q = 0; q < 4; ++q)
#pragma unroll
    for (int j = 0; j < 2; ++j) {
      acc[MH * 4 + q][NH * 2 + j] = __builtin_amdgcn_mfma_f32_16x16x32_bf16(
          af[q][0], bv[j][0], acc[MH * 4 + q][NH * 2 + j], 0, 0, 0);
      acc[MH * 4 + q][NH * 2 + j] = __builtin_amdgcn_mfma_f32_16x16x32_bf16(
          af[q][1], bv[j][1], acc[MH * 4 + q][NH * 2 + j], 0, 0, 0);
    }
  __builtin_amdgcn_s_setprio(0);
  asm volatile("" ::: "memory");
  __builtin_amdgcn_s_barrier();
  asm volatile("" ::: "memory");
}

// EPI: 0 = store bf16; 1 = silu(G)*acc -> bf16 in-place; 2 = atomicAdd f32
template <int EPI>
__global__ __launch_bounds__(512, 2) void gemm8_nt_k(
    const __hip_bfloat16* __restrict__ A, const __hip_bfloat16* __restrict__ B,
    void* __restrict__ Cv, const __hip_bfloat16* __restrict__ Gin,
    int M, int N, int Kfull, int Kloc, int ksplit) {
  __shared__ __align__(16) char lds[131072];

  const int tid = threadIdx.x;
  const int lane = tid & 63;
  const int wid = tid >> 6;
  const int wm = wid >> 2, wn = wid & 3;

  // bijective XCD swizzle (grid %8==0 for all our shapes), then decode
  const int nbn = N >> 8;
  const int nwg2 = (M >> 8) * nbn;
  const int G = nwg2 * ksplit;
  const int q8 = G >> 3;
  const int bid = blockIdx.x;
  const int wg = (bid & 7) * q8 + (bid >> 3);
  const int kh = wg / nwg2;
  const int rem = wg - kh * nwg2;
  const int bm = rem / nbn;
  const int bn = rem - bm * nbn;

  const size_t Kb = (size_t)Kfull * 2;  // global row stride bytes
  const size_t koffb = (size_t)kh * Kloc * 2;

  // staging geometry: per call, wave wid covers rows [wid*8, wid*8+8)
  const int srow = lane >> 3;
  const int scw = ((lane & 7) ^ srow) << 4;  // pre-swizzled source col
  const uint8_t* gA = (const uint8_t*)A +
      (size_t)(bm * 256 + wid * 8 + srow) * Kb + koffb + scw;
  const uint8_t* gB = (const uint8_t*)B +
      (size_t)(bn * 256 + wid * 8 + srow) * Kb + koffb + scw;
  char* ldsw = lds + wid * 1024;  // wave-uniform LDS dest base

  auto stageA = [&](int h, int b, int tt) {
    const uint8_t* g = gA + (size_t)(h * 128) * Kb + (size_t)tt * 128;
    char* l = ldsw + b * 32768 + h * 16384;
    g2l16(g, l);
    g2l16(g + 64 * Kb, l + 8192);
  };
  auto stageB = [&](int h, int b, int tt) {
    const uint8_t* g = gB + (size_t)(h * 128) * Kb + (size_t)tt * 128;
    char* l = ldsw + 65536 + b * 32768 + h * 16384;
    g2l16(g, l);
    g2l16(g + 64 * Kb, l + 8192);
  };

  // fragment read bases (swizzled): row*128 + ((lanegrp<<4) ^ ((row&7)<<4))
  const int colsw = (((lane >> 4) << 4) ^ ((lane & 7) << 4));
  const char* aRd = lds + (wm * 64 + (lane & 15)) * 128 + colsw;
  const char* bRd = lds + 65536 + (wn * 32 + (lane & 15)) * 128 + colsw;

  f32x4 acc[8][4] = {};

  const int nt = Kloc >> 6;
  const int niter = nt >> 1;

  // prologue: tile0 complete + tile1 halves h0 (A,B)
  stageA(0, 0, 0); stageA(1, 0, 0); stageB(0, 0, 0); stageB(1, 0, 0);
  stageA(0, 1, 1); stageB(0, 1, 1);
  asm volatile("s_waitcnt vmcnt(4)" ::: "memory");
  __builtin_amdgcn_s_barrier();
  asm volatile("" ::: "memory");

  for (int i = 0; i < niter - 1; ++i) {
    const int t = i * 2;
    phase8<0, 0, 0, -1>(aRd, bRd, acc, [&] { stageA(1, 1, t + 1); });
    phase8<0, 0, 1, -1>(aRd, bRd, acc, [&] { stageB(1, 1, t + 1); });
    phase8<0, 1, 0, -1>(aRd, bRd, acc, [&] { stageA(0, 0, t + 2); });
    phase8<0, 1, 1,  4>(aRd, bRd, acc, [&] { stageB(0, 0, t + 2); });
    phase8<1, 0, 0, -1>(aRd, bRd, acc, [&] { stageA(1, 0, t + 2); });
    phase8<1, 0, 1, -1>(aRd, bRd, acc, [&] { stageB(1, 0, t + 2); });
    phase8<1, 1, 0, -1>(aRd, bRd, acc, [&] { stageA(0, 1, t + 3); });
    phase8<1, 1, 1,  4>(aRd, bRd, acc, [&] { stageB(0, 1, t + 3); });
  }
  {  // tail iteration: tiles nt-2 (buf0), nt-1 (buf1); no OOB staging
    const int t = nt - 2;
    phase8<0, 0, 0, -1>(aRd, bRd, acc, [&] { stageA(1, 1, t + 1); });
    phase8<0, 0, 1, -1>(aRd, bRd, acc, [&] { stageB(1, 1, t + 1); });
    phase8<0, 1, 0, -1>(aRd, bRd, acc, [&] {});
    phase8<0, 1, 1,  0>(aRd, bRd, acc, [&] {});
    phase8<1, 0, 0, -1>(aRd, bRd, acc, [&] {});
    phase8<1, 0, 1, -1>(aRd, bRd, acc, [&] {});
    phase8<1, 1, 0, -1>(aRd, bRd, acc, [&] {});
    phase8<1, 1, 1, -1>(aRd, bRd, acc, [&] {});
  }

  // epilogue: C/D frag layout col=lane&15, row=(lane>>4)*4+r
#pragma unroll
  for (int mi = 0; mi < 8; ++mi) {
    const int grow0 = bm * 256 + (mi >> 2) * 128 + wm * 64 + (mi & 3) * 16 +
                      ((lane >> 4) << 2);
#pragma unroll
    for (int ni = 0; ni < 4; ++ni) {
      const int gcol = bn * 256 + (ni >> 1) * 128 + wn * 32 + (ni & 1) * 16 +
                       (lane & 15);
#pragma unroll
      for (int r = 0; r < 4; ++r) {
        const size_t idx = (size_t)(grow0 + r) * N + gcol;
        const float v = acc[mi][ni][r];
        if (EPI == 0) {
          ((__hip_bfloat16*)Cv)[idx] = __float2bfloat16(v);
        } else if (EPI == 1) {
          const float g = __bfloat162float(Gin[idx]);
          ((__hip_bfloat16*)Cv)[idx] =
              __float2bfloat16(g / (1.0f + __expf(-g)) * v);
        } else {
          atomicAdd(&((float*)Cv)[idx], v);
        }
      }
    }
  }
}

// ---------------------------------------------------------------- launcher
extern "C" void kernel_launch(void* const* d_in, const int* in_sizes, int n_in,
                              void* d_out, int out_size, void* d_ws,
                              size_t ws_size, hipStream_t stream) {
  const float* x = (const float*)d_in[0];
  const int* gate_codes = (const int*)d_in[1];
  const float* gate_absmax = (const float*)d_in[2];
  const int* up_codes = (const int*)d_in[3];
  const float* up_absmax = (const float*)d_in[4];
  const int* down_codes = (const int*)d_in[5];
  const float* down_absmax = (const float*)d_in[6];

  char* ws = (char*)d_ws;
  __hip_bfloat16* xb = (__hip_bfloat16*)ws;                       // 16 MB
  __hip_bfloat16* Wb = (__hip_bfloat16*)(ws + (size_t)TDIM * HDIM * 2);  // 112 MB
  __hip_bfloat16* Hb = (__hip_bfloat16*)(ws + (size_t)TDIM * HDIM * 2 +
                                         (size_t)MDIM * HDIM * 2);       // 56 MB

  // down GEMM accumulates atomically -> zero d_out each call
  hipMemsetAsync(d_out, 0, (size_t)TDIM * HDIM * 4, stream);

  f32_to_bf16_k<<<2048, 256, 0, stream>>>(x, xb, (TDIM * HDIM) / 8);

  // gate
  dequant_nf4_k<<<MDIM, 256, 0, stream>>>(gate_codes, gate_absmax, Wb, HDIM);
  gemm8_nt_k<0><<<(TDIM / 256) * (MDIM / 256), 512, 0, stream>>>(
      xb, Wb, Hb, nullptr, TDIM, MDIM, HDIM, HDIM, 1);
  // up + swiglu
  dequant_nf4_k<<<MDIM, 256, 0, stream>>>(up_codes, up_absmax, Wb, HDIM);
  gemm8_nt_k<1><<<(TDIM / 256) * (MDIM / 256), 512, 0, stream>>>(
      xb, Wb, Hb, Hb, TDIM, MDIM, HDIM, HDIM, 1);
  // down, split-K=2 (grid 256 = full GPU), atomic f32 epilogue
  dequant_nf4_k<<<HDIM, 256, 0, stream>>>(down_codes, down_absmax, Wb, MDIM);
  gemm8_nt_k<2><<<2 * (TDIM / 256) * (HDIM / 256), 512, 0, stream>>>(
      Hb, Wb, (float*)d_out, nullptr, TDIM, HDIM, MDIM, MDIM / 2, 2);
}

// Round 3
// 1797.877 us; speedup vs baseline: 1.0342x; 1.0342x over previous
//
#include <hip/hip_runtime.h>
#include <hip/hip_bf16.h>
#include <cstdint>
#include <cstddef>

// Problem dims (fixed by setup_inputs)
#define TDIM 2048
#define HDIM 4096
#define MDIM 14336

typedef __attribute__((ext_vector_type(8))) __bf16 bf16x8;
typedef __attribute__((ext_vector_type(4))) float f32x4;

#define MEMFENCE asm volatile("" ::: "memory")

__device__ __constant__ float NF4_LUT[16] = {
    -1.0f, -0.6961928009986877f, -0.5250730514526367f, -0.39491748809814453f,
    -0.28444138169288635f, -0.18477343022823334f, -0.09105003625154495f, 0.0f,
    0.07958029955625534f, 0.16093020141124725f, 0.24611230194568634f,
    0.33791524171829224f, 0.44070982933044434f, 0.5626170039176941f,
    0.7229568362236023f, 1.0f};

__device__ __forceinline__ void g2l16(const void* g, void* l) {
  __builtin_amdgcn_global_load_lds(
      (const __attribute__((address_space(1))) unsigned int*)g,
      (__attribute__((address_space(3))) unsigned int*)l, 16, 0, 0);
}

template <int VM>
__device__ __forceinline__ void vmwait() {
  if (VM == 4) asm volatile("s_waitcnt vmcnt(4)" ::: "memory");
  if (VM == 0) asm volatile("s_waitcnt vmcnt(0)" ::: "memory");
}

// ------------------------------------------------------------ x f32 -> bf16
__global__ __launch_bounds__(256) void f32_to_bf16_k(
    const float* __restrict__ in, __hip_bfloat16* __restrict__ out, int n8) {
  for (int i = blockIdx.x * 256 + threadIdx.x; i < n8; i += gridDim.x * 256) {
    const float4* p = (const float4*)(in + (size_t)i * 8);
    float4 a = p[0], b = p[1];
    union { __hip_bfloat16 h[8]; int4 v; } u;
    u.h[0] = __float2bfloat16(a.x);
    u.h[1] = __float2bfloat16(a.y);
    u.h[2] = __float2bfloat16(a.z);
    u.h[3] = __float2bfloat16(a.w);
    u.h[4] = __float2bfloat16(b.x);
    u.h[5] = __float2bfloat16(b.y);
    u.h[6] = __float2bfloat16(b.z);
    u.h[7] = __float2bfloat16(b.w);
    *(int4*)(out + (size_t)i * 8) = u.v;
  }
}

// --------------------------------------------------- NF4 dequant -> bf16 W
__global__ __launch_bounds__(256) void dequant_nf4_k(
    const int* __restrict__ codes, const float* __restrict__ absmax,
    __hip_bfloat16* __restrict__ W, int K) {
  __shared__ float lut[16];
  if (threadIdx.x < 16) lut[threadIdx.x] = NF4_LUT[threadIdx.x];
  __syncthreads();
  const int row = blockIdx.x;
  const int K8 = K >> 3;
  const size_t rbase = (size_t)row * K;
  for (int c8 = threadIdx.x; c8 < K8; c8 += 256) {
    const int col = c8 << 3;
    const float am = absmax[(size_t)row * (K >> 6) + (col >> 6)];
    const int4* cp = (const int4*)(codes + rbase + col);
    int4 ca = cp[0], cb = cp[1];
    union { __hip_bfloat16 h[8]; int4 v; } u;
    u.h[0] = __float2bfloat16(lut[ca.x & 15] * am);
    u.h[1] = __float2bfloat16(lut[ca.y & 15] * am);
    u.h[2] = __float2bfloat16(lut[ca.z & 15] * am);
    u.h[3] = __float2bfloat16(lut[ca.w & 15] * am);
    u.h[4] = __float2bfloat16(lut[cb.x & 15] * am);
    u.h[5] = __float2bfloat16(lut[cb.y & 15] * am);
    u.h[6] = __float2bfloat16(lut[cb.z & 15] * am);
    u.h[7] = __float2bfloat16(lut[cb.w & 15] * am);
    *(int4*)(W + rbase + col) = u.v;
  }
}

// ------------------------------------------------------- 8-phase 256² GEMM
// C[M,N] (+)= A[M,K] @ B[N,K]^T, bf16 in, f32 acc. 512 thr = 8 waves (2x4).
// LDS 128KB: [A | B], each 2 buf x 2 half x (128 rows x 128B swizzled).
// Per K-tile: 4 phases in ZIGZAG quadrant order with held fragments:
//   P0: read af(h0) 8 + bv0(h0) 4 -> quad(0,0)
//   P1: read bv1(h1) 4            -> quad(0,1)  [af held]
//   P2: read af(h1) 8             -> quad(1,1)  [bv1 held]
//   P3: no reads                  -> quad(1,0)  [af(h1), bv0 held]
// 24 ds_read_b128/wave/K-tile = minimal (no redundancy).
// Stage map unchanged (iteration = tiles t[buf0], t+1[buf1]):
//  p0:A(t+1,h1,b1) p1:B(t+1,h1,b1) p2:A(t+2,h0,b0) p3:B(t+2,h0,b0)+vmcnt(4)
//  p4:A(t+2,h1,b0) p5:B(t+2,h1,b0) p6:A(t+3,h0,b1) p7:B(t+3,h0,b1)+vmcnt(4)
template <int B_, int VM3, typename F0, typename F1, typename F2, typename F3>
__device__ __forceinline__ void ktile4(const char* aRd, const char* bRd,
                                       f32x4 (&acc)[8][4],
                                       F0&& s0, F1&& s1, F2&& s2, F3&& s3) {
  const char* ab = aRd + B_ * 32768;
  const char* bb = bRd + B_ * 32768;
  bf16x8 af[4][2], bv0[2][2], bv1[2][2];
#define LDA(H, Q, KS) \
  (*(const bf16x8*)((uintptr_t)(ab + (H)*16384 + (Q)*2048) ^ ((KS) << 6)))
#define LDB(H, J, KS) \
  (*(const bf16x8*)((uintptr_t)(bb + (H)*16384 + (J)*2048) ^ ((KS) << 6)))
#define MFMA_(a_, b_, c_) __builtin_amdgcn_mfma_f32_16x16x32_bf16(a_, b_, c_, 0, 0, 0)

  // ---- P0: quad (0,0)
#pragma unroll
  for (int q = 0; q < 4; ++q) { af[q][0] = LDA(0, q, 0); af[q][1] = LDA(0, q, 1); }
#pragma unroll
  for (int j = 0; j < 2; ++j) { bv0[j][0] = LDB(0, j, 0); bv0[j][1] = LDB(0, j, 1); }
  s0();
  MEMFENCE; __builtin_amdgcn_s_barrier(); MEMFENCE;
  __builtin_amdgcn_s_setprio(1);
#pragma unroll
  for (int q = 0; q < 4; ++q)
#pragma unroll
    for (int j = 0; j < 2; ++j) {
      acc[q][j] = MFMA_(af[q][0], bv0[j][0], acc[q][j]);
      acc[q][j] = MFMA_(af[q][1], bv0[j][1], acc[q][j]);
    }
  __builtin_amdgcn_s_setprio(0);
  MEMFENCE; __builtin_amdgcn_s_barrier(); MEMFENCE;

  // ---- P1: quad (0,1), af held
#pragma unroll
  for (int j = 0; j < 2; ++j) { bv1[j][0] = LDB(1, j, 0); bv1[j][1] = LDB(1, j, 1); }
  s1();
  MEMFENCE; __builtin_amdgcn_s_barrier(); MEMFENCE;
  __builtin_amdgcn_s_setprio(1);
#pragma unroll
  for (int q = 0; q < 4; ++q)
#pragma unroll
    for (int j = 0; j < 2; ++j) {
      acc[q][2 + j] = MFMA_(af[q][0], bv1[j][0], acc[q][2 + j]);
      acc[q][2 + j] = MFMA_(af[q][1], bv1[j][1], acc[q][2 + j]);
    }
  __builtin_amdgcn_s_setprio(0);
  MEMFENCE; __builtin_amdgcn_s_barrier(); MEMFENCE;

  // ---- P2: quad (1,1), bv1 held, af overwritten with h1
#pragma unroll
  for (int q = 0; q < 4; ++q) { af[q][0] = LDA(1, q, 0); af[q][1] = LDA(1, q, 1); }
  s2();
  MEMFENCE; __builtin_amdgcn_s_barrier(); MEMFENCE;
  __builtin_amdgcn_s_setprio(1);
#pragma unroll
  for (int q = 0; q < 4; ++q)
#pragma unroll
    for (int j = 0; j < 2; ++j) {
      acc[4 + q][2 + j] = MFMA_(af[q][0], bv1[j][0], acc[4 + q][2 + j]);
      acc[4 + q][2 + j] = MFMA_(af[q][1], bv1[j][1], acc[4 + q][2 + j]);
    }
  __builtin_amdgcn_s_setprio(0);
  MEMFENCE; __builtin_amdgcn_s_barrier(); MEMFENCE;

  // ---- P3: quad (1,0), af(h1) + bv0 held, no LDS reads
  s3();
  vmwait<VM3>();
  MEMFENCE; __builtin_amdgcn_s_barrier(); MEMFENCE;
  __builtin_amdgcn_s_setprio(1);
#pragma unroll
  for (int q = 0; q < 4; ++q)
#pragma unroll
    for (int j = 0; j < 2; ++j) {
      acc[4 + q][j] = MFMA_(af[q][0], bv0[j][0], acc[4 + q][j]);
      acc[4 + q][j] = MFMA_(af[q][1], bv0[j][1], acc[4 + q][j]);
    }
  __builtin_amdgcn_s_setprio(0);
  MEMFENCE; __builtin_amdgcn_s_barrier(); MEMFENCE;
#undef LDA
#undef LDB
#undef MFMA_
}

// EPI: 0 = store bf16; 1 = silu(G)*acc -> bf16 in-place; 2 = atomicAdd f32
template <int EPI>
__global__ __launch_bounds__(512, 2) void gemm8_nt_k(
    const __hip_bfloat16* __restrict__ A, const __hip_bfloat16* __restrict__ B,
    void* __restrict__ Cv, const __hip_bfloat16* __restrict__ Gin,
    int M, int N, int Kfull, int Kloc, int ksplit) {
  __shared__ __align__(16) char lds[131072];

  const int tid = threadIdx.x;
  const int lane = tid & 63;
  const int wid = tid >> 6;
  const int wm = wid >> 2, wn = wid & 3;

  // bijective XCD swizzle (grid %8==0 for all our shapes), then decode
  const int nbn = N >> 8;
  const int nwg2 = (M >> 8) * nbn;
  const int G = nwg2 * ksplit;
  const int q8 = G >> 3;
  const int bid = blockIdx.x;
  const int wg = (bid & 7) * q8 + (bid >> 3);
  const int kh = wg / nwg2;
  const int rem = wg - kh * nwg2;
  const int bm = rem / nbn;
  const int bn = rem - bm * nbn;

  const size_t Kb = (size_t)Kfull * 2;  // global row stride bytes
  const size_t koffb = (size_t)kh * Kloc * 2;

  // staging geometry: per call, wave wid covers rows [wid*8, wid*8+8)
  const int srow = lane >> 3;
  const int scw = ((lane & 7) ^ srow) << 4;  // pre-swizzled source col
  const uint8_t* gA = (const uint8_t*)A +
      (size_t)(bm * 256 + wid * 8 + srow) * Kb + koffb + scw;
  const uint8_t* gB = (const uint8_t*)B +
      (size_t)(bn * 256 + wid * 8 + srow) * Kb + koffb + scw;
  char* ldsw = lds + wid * 1024;  // wave-uniform LDS dest base

  auto stageA = [&](int h, int b, int tt) {
    const uint8_t* g = gA + (size_t)(h * 128) * Kb + (size_t)tt * 128;
    char* l = ldsw + b * 32768 + h * 16384;
    g2l16(g, l);
    g2l16(g + 64 * Kb, l + 8192);
  };
  auto stageB = [&](int h, int b, int tt) {
    const uint8_t* g = gB + (size_t)(h * 128) * Kb + (size_t)tt * 128;
    char* l = ldsw + 65536 + b * 32768 + h * 16384;
    g2l16(g, l);
    g2l16(g + 64 * Kb, l + 8192);
  };

  // fragment read bases (swizzled): row*128 + ((lanegrp<<4) ^ ((row&7)<<4))
  const int colsw = (((lane >> 4) << 4) ^ ((lane & 7) << 4));
  const char* aRd = lds + (wm * 64 + (lane & 15)) * 128 + colsw;
  const char* bRd = lds + 65536 + (wn * 32 + (lane & 15)) * 128 + colsw;

  f32x4 acc[8][4] = {};

  const int nt = Kloc >> 6;
  const int niter = nt >> 1;

  // prologue: tile0 complete + tile1 halves h0 (A,B)
  stageA(0, 0, 0); stageA(1, 0, 0); stageB(0, 0, 0); stageB(1, 0, 0);
  stageA(0, 1, 1); stageB(0, 1, 1);
  asm volatile("s_waitcnt vmcnt(4)" ::: "memory");
  __builtin_amdgcn_s_barrier();
  MEMFENCE;

  for (int i = 0; i < niter - 1; ++i) {
    const int t = i * 2;
    ktile4<0, 4>(aRd, bRd, acc,
                 [&] { stageA(1, 1, t + 1); }, [&] { stageB(1, 1, t + 1); },
                 [&] { stageA(0, 0, t + 2); }, [&] { stageB(0, 0, t + 2); });
    ktile4<1, 4>(aRd, bRd, acc,
                 [&] { stageA(1, 0, t + 2); }, [&] { stageB(1, 0, t + 2); },
                 [&] { stageA(0, 1, t + 3); }, [&] { stageB(0, 1, t + 3); });
  }
  {  // tail: tiles nt-2 (buf0), nt-1 (buf1); no OOB staging
    ktile4<0, 0>(aRd, bRd, acc,
                 [&] { stageA(1, 1, nt - 1); }, [&] { stageB(1, 1, nt - 1); },
                 [&] {}, [&] {});
    ktile4<1, -1>(aRd, bRd, acc, [&] {}, [&] {}, [&] {}, [&] {});
  }

  // epilogue: C/D frag layout col=lane&15, row=(lane>>4)*4+r
#pragma unroll
  for (int mi = 0; mi < 8; ++mi) {
    const int grow0 = bm * 256 + (mi >> 2) * 128 + wm * 64 + (mi & 3) * 16 +
                      ((lane >> 4) << 2);
#pragma unroll
    for (int ni = 0; ni < 4; ++ni) {
      const int gcol = bn * 256 + (ni >> 1) * 128 + wn * 32 + (ni & 1) * 16 +
                       (lane & 15);
#pragma unroll
      for (int r = 0; r < 4; ++r) {
        const size_t idx = (size_t)(grow0 + r) * N + gcol;
        const float v = acc[mi][ni][r];
        if (EPI == 0) {
          ((__hip_bfloat16*)Cv)[idx] = __float2bfloat16(v);
        } else if (EPI == 1) {
          const float g = __bfloat162float(Gin[idx]);
          ((__hip_bfloat16*)Cv)[idx] =
              __float2bfloat16(g / (1.0f + __expf(-g)) * v);
        } else {
          atomicAdd(&((float*)Cv)[idx], v);
        }
      }
    }
  }
}

// ---------------------------------------------------------------- launcher
extern "C" void kernel_launch(void* const* d_in, const int* in_sizes, int n_in,
                              void* d_out, int out_size, void* d_ws,
                              size_t ws_size, hipStream_t stream) {
  const float* x = (const float*)d_in[0];
  const int* gate_codes = (const int*)d_in[1];
  const float* gate_absmax = (const float*)d_in[2];
  const int* up_codes = (const int*)d_in[3];
  const float* up_absmax = (const float*)d_in[4];
  const int* down_codes = (const int*)d_in[5];
  const float* down_absmax = (const float*)d_in[6];

  char* ws = (char*)d_ws;
  __hip_bfloat16* xb = (__hip_bfloat16*)ws;                              // 16 MB
  __hip_bfloat16* Wb = (__hip_bfloat16*)(ws + (size_t)TDIM * HDIM * 2);  // 112 MB
  __hip_bfloat16* Hb = (__hip_bfloat16*)(ws + (size_t)TDIM * HDIM * 2 +
                                         (size_t)MDIM * HDIM * 2);       // 56 MB

  // down GEMM accumulates atomically -> zero d_out each call
  hipMemsetAsync(d_out, 0, (size_t)TDIM * HDIM * 4, stream);

  f32_to_bf16_k<<<2048, 256, 0, stream>>>(x, xb, (TDIM * HDIM) / 8);

  // gate
  dequant_nf4_k<<<MDIM, 256, 0, stream>>>(gate_codes, gate_absmax, Wb, HDIM);
  gemm8_nt_k<0><<<(TDIM / 256) * (MDIM / 256), 512, 0, stream>>>(
      xb, Wb, Hb, nullptr, TDIM, MDIM, HDIM, HDIM, 1);
  // up + swiglu
  dequant_nf4_k<<<MDIM, 256, 0, stream>>>(up_codes, up_absmax, Wb, HDIM);
  gemm8_nt_k<1><<<(TDIM / 256) * (MDIM / 256), 512, 0, stream>>>(
      xb, Wb, Hb, Hb, TDIM, MDIM, HDIM, HDIM, 1);
  // down, split-K=2 (grid 256 = full GPU), atomic f32 epilogue
  dequant_nf4_k<<<HDIM, 256, 0, stream>>>(down_codes, down_absmax, Wb, MDIM);
  gemm8_nt_k<2><<<2 * (TDIM / 256) * (HDIM / 256), 512, 0, stream>>>(
      Hb, Wb, (float*)d_out, nullptr, TDIM, HDIM, MDIM, MDIM / 2, 2);
}

// Round 4
// 1133.274 us; speedup vs baseline: 1.6407x; 1.5864x over previous
//
#include <hip/hip_runtime.h>
#include <hip/hip_bf16.h>
#include <cstdint>
#include <cstddef>

// Problem dims (fixed by setup_inputs)
#define TDIM 2048
#define HDIM 4096
#define MDIM 14336

typedef __attribute__((ext_vector_type(8))) __bf16 bf16x8;
typedef __attribute__((ext_vector_type(4))) float f32x4;

__device__ __constant__ float NF4_LUT[16] = {
    -1.0f, -0.6961928009986877f, -0.5250730514526367f, -0.39491748809814453f,
    -0.28444138169288635f, -0.18477343022823334f, -0.09105003625154495f, 0.0f,
    0.07958029955625534f, 0.16093020141124725f, 0.24611230194568634f,
    0.33791524171829224f, 0.44070982933044434f, 0.5626170039176941f,
    0.7229568362236023f, 1.0f};

__device__ __forceinline__ void g2l16(const void* g, void* l) {
  __builtin_amdgcn_global_load_lds(
      (const __attribute__((address_space(1))) unsigned int*)g,
      (__attribute__((address_space(3))) unsigned int*)l, 16, 0, 0);
}

// ------------------------------------------------------------ x f32 -> bf16
__global__ __launch_bounds__(256) void f32_to_bf16_k(
    const float* __restrict__ in, __hip_bfloat16* __restrict__ out, int n8) {
  for (int i = blockIdx.x * 256 + threadIdx.x; i < n8; i += gridDim.x * 256) {
    const float4* p = (const float4*)(in + (size_t)i * 8);
    float4 a = p[0], b = p[1];
    union { __hip_bfloat16 h[8]; int4 v; } u;
    u.h[0] = __float2bfloat16(a.x);
    u.h[1] = __float2bfloat16(a.y);
    u.h[2] = __float2bfloat16(a.z);
    u.h[3] = __float2bfloat16(a.w);
    u.h[4] = __float2bfloat16(b.x);
    u.h[5] = __float2bfloat16(b.y);
    u.h[6] = __float2bfloat16(b.z);
    u.h[7] = __float2bfloat16(b.w);
    *(int4*)(out + (size_t)i * 8) = u.v;
  }
}

// --------------------------------------------------- NF4 dequant -> bf16 W
__global__ __launch_bounds__(256) void dequant_nf4_k(
    const int* __restrict__ codes, const float* __restrict__ absmax,
    __hip_bfloat16* __restrict__ W, int K) {
  __shared__ float lut[16];
  if (threadIdx.x < 16) lut[threadIdx.x] = NF4_LUT[threadIdx.x];
  __syncthreads();
  const int row = blockIdx.x;
  const int K8 = K >> 3;
  const size_t rbase = (size_t)row * K;
  for (int c8 = threadIdx.x; c8 < K8; c8 += 256) {
    const int col = c8 << 3;
    const float am = absmax[(size_t)row * (K >> 6) + (col >> 6)];
    const int4* cp = (const int4*)(codes + rbase + col);
    int4 ca = cp[0], cb = cp[1];
    union { __hip_bfloat16 h[8]; int4 v; } u;
    u.h[0] = __float2bfloat16(lut[ca.x & 15] * am);
    u.h[1] = __float2bfloat16(lut[ca.y & 15] * am);
    u.h[2] = __float2bfloat16(lut[ca.z & 15] * am);
    u.h[3] = __float2bfloat16(lut[ca.w & 15] * am);
    u.h[4] = __float2bfloat16(lut[cb.x & 15] * am);
    u.h[5] = __float2bfloat16(lut[cb.y & 15] * am);
    u.h[6] = __float2bfloat16(lut[cb.z & 15] * am);
    u.h[7] = __float2bfloat16(lut[cb.w & 15] * am);
    *(int4*)(W + rbase + col) = u.v;
  }
}

// --------------------------------------------- m97-style GEMM, 256x128 tile
// C[M,N] (+)= A[M,K] @ B[N,K]^T, bf16 in, f32 acc.
// 512 thr = 8 waves (4 wm x 2 wn); per-wave output 64x64 (acc[4][4]).
// Single-buffered LDS 48KB (A 32K + B 16K) -> 2 blocks/CU (multi-block
// overlap = the m97 mechanism; compiler schedules waitcnts).
// Swizzle: pre-swizzled global source col ((slot^row8)<<4) + swizzled read
// (col ^ ((row&7)<<4)) — verified in round 1.
// EPI: 0 = store bf16; 1 = silu(G)*acc -> bf16 in-place; 2 = atomicAdd f32
template <int EPI>
__global__ __launch_bounds__(512, 4) void gemm97_nt_k(
    const __hip_bfloat16* __restrict__ A, const __hip_bfloat16* __restrict__ B,
    void* __restrict__ Cv, const __hip_bfloat16* __restrict__ Gin,
    int M, int N, int Kfull, int Kloc, int ksplit) {
  __shared__ __align__(16) char sA[256 * 128];  // 256 rows x 128B (64 bf16)
  __shared__ __align__(16) char sB[128 * 128];  // 128 rows x 128B

  const int tid = threadIdx.x;
  const int lane = tid & 63;
  const int wid = tid >> 6;
  const int wm = wid >> 1, wn = wid & 1;

  // bijective XCD swizzle (grid %8==0 for all our shapes), then decode
  const int nbn = N >> 7;                 // BN=128
  const int nwg2 = (M >> 8) * nbn;        // BM=256
  const int G = nwg2 * ksplit;
  const int q8 = G >> 3;
  const int bid = blockIdx.x;
  const int wg = (bid & 7) * q8 + (bid >> 3);
  const int kh = wg / nwg2;
  const int rem = wg - kh * nwg2;
  const int bm = rem / nbn;
  const int bn = rem - bm * nbn;

  const size_t Kb = (size_t)Kfull * 2;  // global row stride bytes
  const size_t koffb = (size_t)kh * Kloc * 2;

  // staging geometry: sweep covers 64 rows (8 waves x 8 rows), 16B/lane
  const int srow = lane >> 3;                 // row within 8-row chunk
  const int scw = ((lane & 7) ^ srow) << 4;   // pre-swizzled source col
  const uint8_t* gA = (const uint8_t*)A +
      (size_t)(bm * 256 + wid * 8 + srow) * Kb + koffb + scw;
  const uint8_t* gB = (const uint8_t*)B +
      (size_t)(bn * 128 + wid * 8 + srow) * Kb + koffb + scw;
  char* lA = sA + wid * 1024;  // wave-uniform LDS dest bases
  char* lB = sB + wid * 1024;

  // fragment read bases (swizzled): row*128 + ((lanegrp<<4) ^ ((row&7)<<4))
  const int colsw = (((lane >> 4) << 4) ^ ((lane & 7) << 4));
  const char* aRd = sA + (wm * 64 + (lane & 15)) * 128 + colsw;
  const char* bRd = sB + (wn * 64 + (lane & 15)) * 128 + colsw;

  f32x4 acc[4][4] = {};

  const int nt = Kloc >> 6;
  for (int kt = 0; kt < nt; ++kt) {
    const size_t kb = (size_t)kt * 128;
#pragma unroll
    for (int s = 0; s < 4; ++s)  // A: 4 sweeps of 64 rows
      g2l16(gA + (size_t)(s * 64) * Kb + kb, lA + s * 8192);
#pragma unroll
    for (int s = 0; s < 2; ++s)  // B: 2 sweeps of 64 rows
      g2l16(gB + (size_t)(s * 64) * Kb + kb, lB + s * 8192);
    __syncthreads();
#pragma unroll
    for (int ks = 0; ks < 2; ++ks) {
      bf16x8 af[4], bv[4];
#pragma unroll
      for (int i = 0; i < 4; ++i) {
        af[i] = *(const bf16x8*)((uintptr_t)(aRd + i * 2048) ^ (ks << 6));
        bv[i] = *(const bf16x8*)((uintptr_t)(bRd + i * 2048) ^ (ks << 6));
      }
#pragma unroll
      for (int mi = 0; mi < 4; ++mi)
#pragma unroll
        for (int nj = 0; nj < 4; ++nj)
          acc[mi][nj] = __builtin_amdgcn_mfma_f32_16x16x32_bf16(
              af[mi], bv[nj], acc[mi][nj], 0, 0, 0);
    }
    __syncthreads();
  }

  // epilogue: C/D frag layout col=lane&15, row=(lane>>4)*4+r
  const int row0 = bm * 256 + wm * 64 + ((lane >> 4) << 2);
  const int col0 = bn * 128 + wn * 64 + (lane & 15);
#pragma unroll
  for (int mi = 0; mi < 4; ++mi) {
#pragma unroll
    for (int nj = 0; nj < 4; ++nj) {
#pragma unroll
      for (int r = 0; r < 4; ++r) {
        const size_t idx =
            (size_t)(row0 + mi * 16 + r) * N + (col0 + nj * 16);
        const float v = acc[mi][nj][r];
        if (EPI == 0) {
          ((__hip_bfloat16*)Cv)[idx] = __float2bfloat16(v);
        } else if (EPI == 1) {
          const float g = __bfloat162float(Gin[idx]);
          ((__hip_bfloat16*)Cv)[idx] =
              __float2bfloat16(g / (1.0f + __expf(-g)) * v);
        } else {
          atomicAdd(&((float*)Cv)[idx], v);
        }
      }
    }
  }
}

// ---------------------------------------------------------------- launcher
extern "C" void kernel_launch(void* const* d_in, const int* in_sizes, int n_in,
                              void* d_out, int out_size, void* d_ws,
                              size_t ws_size, hipStream_t stream) {
  const float* x = (const float*)d_in[0];
  const int* gate_codes = (const int*)d_in[1];
  const float* gate_absmax = (const float*)d_in[2];
  const int* up_codes = (const int*)d_in[3];
  const float* up_absmax = (const float*)d_in[4];
  const int* down_codes = (const int*)d_in[5];
  const float* down_absmax = (const float*)d_in[6];

  char* ws = (char*)d_ws;
  __hip_bfloat16* xb = (__hip_bfloat16*)ws;                              // 16 MB
  __hip_bfloat16* Wb = (__hip_bfloat16*)(ws + (size_t)TDIM * HDIM * 2);  // 112 MB
  __hip_bfloat16* Hb = (__hip_bfloat16*)(ws + (size_t)TDIM * HDIM * 2 +
                                         (size_t)MDIM * HDIM * 2);       // 56 MB

  // down GEMM accumulates atomically -> zero d_out each call
  hipMemsetAsync(d_out, 0, (size_t)TDIM * HDIM * 4, stream);

  f32_to_bf16_k<<<2048, 256, 0, stream>>>(x, xb, (TDIM * HDIM) / 8);

  // gate: grid 8 x 112 = 896
  dequant_nf4_k<<<MDIM, 256, 0, stream>>>(gate_codes, gate_absmax, Wb, HDIM);
  gemm97_nt_k<0><<<(TDIM / 256) * (MDIM / 128), 512, 0, stream>>>(
      xb, Wb, Hb, nullptr, TDIM, MDIM, HDIM, HDIM, 1);
  // up + swiglu
  dequant_nf4_k<<<MDIM, 256, 0, stream>>>(up_codes, up_absmax, Wb, HDIM);
  gemm97_nt_k<1><<<(TDIM / 256) * (MDIM / 128), 512, 0, stream>>>(
      xb, Wb, Hb, Hb, TDIM, MDIM, HDIM, HDIM, 1);
  // down, split-K=2: grid 2 x 8 x 32 = 512 (exactly 1 round at 2 blk/CU)
  dequant_nf4_k<<<HDIM, 256, 0, stream>>>(down_codes, down_absmax, Wb, MDIM);
  gemm97_nt_k<2><<<2 * (TDIM / 256) * (HDIM / 128), 512, 0, stream>>>(
      Hb, Wb, (float*)d_out, nullptr, TDIM, HDIM, MDIM, MDIM / 2, 2);
}